// Round 1
// baseline (206.866 us; speedup 1.0000x reference)
//
#include <hip/hip_runtime.h>

typedef __bf16 bf16;
typedef bf16 bf16x8 __attribute__((ext_vector_type(8)));
typedef float f32x4 __attribute__((ext_vector_type(4)));
typedef unsigned int u32;

#define PTS 16          // points per block (4 per wave)
#define WREG 4800       // per-wave LDS region bytes (12 T-rows x 400B pitch)
// Region phases (aliased, wave-private except T reads):
//   phase 0 (stage):  [0,3072)  X for wave's 4 pts (gld_lds; consumed to regs before T writes)
//   phase 1 (gemm A): [0,4800)  T = 12 rows x 400B (row m = wave*12 + q*3 + i)
//   phase 2 (after barrier2): [0,3072) Y staging, 16 pts x 48 floats (wave's 16 f-cols)
// LDS total 4*4800 = 19200 B -> 8 blocks/CU at VGPR<=64 (7 at <=72), vs 4 before.
// J is NOT staged: direct 24B/lane strided loads (L1 merges; HBM util is only 20%).

__device__ __forceinline__ void gld_lds16(const void* g, void* l) {
    __builtin_amdgcn_global_load_lds(
        (const __attribute__((address_space(1))) u32*)g,
        (__attribute__((address_space(3))) u32*)l, 16, 0, 0);
}

__global__ __launch_bounds__(256, 7)
void affine_linear_fused(const float* __restrict__ X, const float* __restrict__ J,
                         const float* __restrict__ A, const float* __restrict__ Bm,
                         const float* __restrict__ C, float* __restrict__ Y)
{
    __shared__ __attribute__((aligned(128))) unsigned char lds[4 * WREG];

    const int tid  = threadIdx.x;
    const int wave = tid >> 6;
    const int lane = tid & 63;
    const int l16  = lane & 15;
    const int lq   = lane >> 4;       // quad 0..3
    const long bn0 = (long)blockIdx.x * PTS;

    unsigned char* wbase = &lds[wave * WREG];

    // ---- X: async coalesced stage, 3 x 1024B -> [0,3072) ----
    const float* xg = X + (bn0 + wave * 4) * 192;
    #pragma unroll
    for (int t = 0; t < 3; ++t)
        gld_lds16(xg + t * 256 + lane * 4, wbase + t * 1024);

    // ---- J: direct strided loads to registers (lane d reads its 6 floats) ----
    const float* jg = J + (bn0 + wave * 4) * 384 + lane * 6;
    float jv[4][6];
    #pragma unroll
    for (int q = 0; q < 4; ++q) {
        float2 ja = *(const float2*)(jg + q * 384 + 0);
        float2 jb = *(const float2*)(jg + q * 384 + 2);
        float2 jc = *(const float2*)(jg + q * 384 + 4);
        jv[q][0] = ja.x; jv[q][1] = ja.y;
        jv[q][2] = jb.x; jv[q][3] = jb.y;
        jv[q][4] = jc.x; jv[q][5] = jc.y;
    }

    // Drain: X stage has no compiler-visible dep; J regs needed now anyway.
    __asm__ volatile("s_waitcnt vmcnt(0)" ::: "memory");

    // ---- X from LDS (stride-3 dwords: odd stride -> 2 lanes/bank, free) ----
    const float* xlds = (const float*)wbase;
    float xv[4][3];
    #pragma unroll
    for (int q = 0; q < 4; ++q) {
        const float* xp = xlds + q * 192 + lane * 3;
        xv[q][0] = xp[0]; xv[q][1] = xp[1]; xv[q][2] = xp[2];
    }

    // ---- Terms; write T rows (aliases the consumed X stage) ----
    #pragma unroll
    for (int q = 0; q < 4; ++q) {
        float a1x = jv[q][0], a2x = jv[q][1];
        float a1y = jv[q][2], a2y = jv[q][3];
        float a1z = jv[q][4], a2z = jv[q][5];
        float xx = xv[q][0], xy = xv[q][1], xz = xv[q][2];

        float n1sq = a1x*a1x + a1y*a1y + a1z*a1z;
        float inv1 = __builtin_amdgcn_rsqf(fmaxf(n1sq, 1e-24f));  // == 1/max(sqrt,1e-12)
        float b1x = a1x*inv1, b1y = a1y*inv1, b1z = a1z*inv1;
        float dot = b1x*a2x + b1y*a2y + b1z*a2z;
        float ux = a2x - dot*b1x, uy = a2y - dot*b1y, uz = a2z - dot*b1z;
        float n2sq = ux*ux + uy*uy + uz*uz;
        float inv2 = __builtin_amdgcn_rsqf(fmaxf(n2sq, 1e-24f));
        float b2x = ux*inv2, b2y = uy*inv2, b2z = uz*inv2;
        float b3x = b1y*b2z - b1z*b2y;
        float b3y = b1z*b2x - b1x*b2z;
        float b3z = b1x*b2y - b1y*b2x;

        float rt0 = b1x*xx + b1y*xy + b1z*xz;
        float rt1 = b2x*xx + b2y*xy + b2z*xz;
        float rt2 = b3x*xx + b3y*xy + b3z*xz;

        float at0 = b1x*rt0 + b2x*rt1;
        float at1 = b1y*rt0 + b2y*rt1;
        float at2 = b1z*rt0 + b2z*rt1;
        float bt0 = b2x*rt0 - b1x*rt1;
        float bt1 = b2y*rt0 - b1y*rt1;
        float bt2 = b2z*rt0 - b1z*rt1;
        float ct0 = b3x*rt2, ct1 = b3y*rt2, ct2 = b3z*rt2;

        bf16* r0 = (bf16*)(wbase + (q*3 + 0) * 400);
        bf16* r1 = (bf16*)(wbase + (q*3 + 1) * 400);
        bf16* r2 = (bf16*)(wbase + (q*3 + 2) * 400);
        r0[lane] = (bf16)at0; r0[64+lane] = (bf16)bt0; r0[128+lane] = (bf16)ct0;
        r1[lane] = (bf16)at1; r1[64+lane] = (bf16)bt1; r1[128+lane] = (bf16)ct1;
        r2[lane] = (bf16)at2; r2[64+lane] = (bf16)bt2; r2[128+lane] = (bf16)ct2;
    }

    // ---- kk=0 W fragment loads issued before barrier (L2 latency hides under it) ----
    const int f = wave * 16 + l16;
    const float* wp0 = A + f * 64 + lq * 8;
    f32x4 wlo = *(const f32x4*)wp0;
    f32x4 whi = *(const f32x4*)(wp0 + 4);

    __syncthreads();   // barrier 1: all T rows visible

    // ---- MFMA: D[m,f] = sum_k T[m,k] * W[f,k]; kk-outer, 2-deep W pipeline ----
    const unsigned char* arow[3];
    #pragma unroll
    for (int mt = 0; mt < 3; ++mt) {
        int m  = mt * 16 + l16;
        int wv = m / 12;
        int r  = m - wv * 12;
        arow[mt] = &lds[wv * WREG + r * 400] + lq * 16;
    }
    f32x4 acc[3];
    #pragma unroll
    for (int mt = 0; mt < 3; ++mt) acc[mt] = (f32x4){0.f, 0.f, 0.f, 0.f};

    #pragma unroll
    for (int kk = 0; kk < 6; ++kk) {
        f32x4 nlo = wlo, nhi = whi;
        if (kk < 5) {
            const float* src = (kk + 1 < 2) ? A : (kk + 1 < 4) ? Bm : C;
            const float* p = src + f * 64 + ((kk + 1) & 1) * 32 + lq * 8;
            nlo = *(const f32x4*)p;
            nhi = *(const f32x4*)(p + 4);
        }
        bf16x8 w;
        w[0] = (bf16)wlo[0]; w[1] = (bf16)wlo[1]; w[2] = (bf16)wlo[2]; w[3] = (bf16)wlo[3];
        w[4] = (bf16)whi[0]; w[5] = (bf16)whi[1]; w[6] = (bf16)whi[2]; w[7] = (bf16)whi[3];
        #pragma unroll
        for (int mt = 0; mt < 3; ++mt) {
            bf16x8 af = *(const bf16x8*)(arow[mt] + kk * 64);
            acc[mt] = __builtin_amdgcn_mfma_f32_16x16x32_bf16(af, w, acc[mt], 0, 0, 0);
        }
        wlo = nlo; whi = nhi;
    }

    __syncthreads();   // barrier 2: all T reads done; region reusable for Y staging

    // ---- Wave-private Y scatter: f-cols [16w,16w+16) => 48-float chunk per point ----
    float* yw = (float*)wbase;
    #pragma unroll
    for (int mt = 0; mt < 3; ++mt) {
        #pragma unroll
        for (int r = 0; r < 4; ++r) {
            int m  = mt * 16 + lq * 4 + r;
            int wv = m / 12;
            int rr = m - wv * 12;
            int q  = rr / 3;
            int i  = rr - q * 3;
            int p  = wv * 4 + q;
            yw[p * 48 + l16 * 3 + i] = acc[mt][r];
        }
    }

    // ---- Wave-private coalesced writeout: 16 chunks of 192 B ----
    const f32x4* ysrc = (const f32x4*)yw;
    #pragma unroll
    for (int v = 0; v < 3; ++v) {
        int vi = v * 64 + lane;           // 0..191
        int p  = vi / 12;
        int vo = vi - p * 12;
        f32x4* dst = (f32x4*)(Y + (bn0 + p) * 192 + wave * 48) + vo;
        *dst = ysrc[vi];
    }
}

extern "C" void kernel_launch(void* const* d_in, const int* in_sizes, int n_in,
                              void* d_out, int out_size, void* d_ws, size_t ws_size,
                              hipStream_t stream) {
    const float* X  = (const float*)d_in[0];
    const float* J  = (const float*)d_in[1];
    const float* A  = (const float*)d_in[2];
    const float* Bm = (const float*)d_in[3];
    const float* C  = (const float*)d_in[4];
    float* Y = (float*)d_out;

    const int points = in_sizes[0] / (64 * 3);   // B*N = 65536
    const int blocks = points / PTS;             // 4096
    affine_linear_fused<<<blocks, 256, 0, stream>>>(X, J, A, Bm, C, Y);
}

// Round 2
// 206.719 us; speedup vs baseline: 1.0007x; 1.0007x over previous
//
#include <hip/hip_runtime.h>

typedef __bf16 bf16;
typedef bf16 bf16x8 __attribute__((ext_vector_type(8)));
typedef float f32x4 __attribute__((ext_vector_type(4)));

#define PTS 16          // points per group (4 per wave)
#define NG 4            // groups per block (grouped-persistent)
#define WREG 4800       // per-wave LDS region bytes (12 T-rows x 400B pitch)
// Per-wave region phases (aliased):
//   T rows  [0,4800): 12 rows x 400B (row = q*3+i), published between barrier1/barrier2
//   Y stage [0,3072): after barrier2, wave-private 16pts x 48 floats
// LDS total 4*4800 = 19200 B. VGPR<=128 (launch_bounds 256,4) -> 16 waves/CU.
// Pipeline: J/X of group g+1 prefetched to registers at top of group g's body;
// raw s_barrier + lgkmcnt(0)-only waits keep those loads in flight across barriers
// (__syncthreads would emit vmcnt(0) and drain the prefetch).

__device__ __forceinline__ void load_group(
    const float* __restrict__ J, const float* __restrict__ X,
    long bn0, int wave, int lane, float jv[4][6], float xv[4][3])
{
    // J: lane d reads its 6 floats (24B stride, 8B-aligned float2 x3)
    const float* jg = J + (bn0 + wave * 4) * 384 + lane * 6;
    #pragma unroll
    for (int q = 0; q < 4; ++q) {
        float2 ja = *(const float2*)(jg + q * 384 + 0);
        float2 jb = *(const float2*)(jg + q * 384 + 2);
        float2 jc2 = *(const float2*)(jg + q * 384 + 4);
        jv[q][0] = ja.x; jv[q][1] = ja.y;
        jv[q][2] = jb.x; jv[q][3] = jb.y;
        jv[q][4] = jc2.x; jv[q][5] = jc2.y;
    }
    // X: lane d reads its 3 floats (12B stride -> only 4B-aligned: scalar loads)
    const float* xg = X + (bn0 + wave * 4) * 192 + lane * 3;
    #pragma unroll
    for (int q = 0; q < 4; ++q) {
        xv[q][0] = xg[q * 192 + 0];
        xv[q][1] = xg[q * 192 + 1];
        xv[q][2] = xg[q * 192 + 2];
    }
}

__global__ __launch_bounds__(256, 4)
void affine_linear_fused(const float* __restrict__ X, const float* __restrict__ J,
                         const float* __restrict__ A, const float* __restrict__ Bm,
                         const float* __restrict__ C, float* __restrict__ Y)
{
    __shared__ __attribute__((aligned(128))) unsigned char lds[4 * WREG];

    const int tid  = threadIdx.x;
    const int wave = tid >> 6;
    const int lane = tid & 63;
    const int l16  = lane & 15;
    const int lq   = lane >> 4;       // quad 0..3
    unsigned char* wbase = &lds[wave * WREG];

    const long gbase = (long)blockIdx.x * NG;

    // ---- Prologue: issue group-0 J/X loads first (needed earliest) ----
    float jc[4][6], xc[4][3];
    load_group(J, X, gbase * PTS, wave, lane, jc, xc);

    // ---- W fragments: loaded + converted ONCE, held in 24 VGPRs ----
    // W[f,k]: f = wave*16+l16; k = kk*32 + lq*8 + j; kk<2:A, <4:Bm, else C
    const int f = wave * 16 + l16;
    bf16x8 wfrag[6];
    #pragma unroll
    for (int kk = 0; kk < 6; ++kk) {
        const float* src = (kk < 2) ? A : (kk < 4) ? Bm : C;
        const f32x4* p4 = (const f32x4*)(src + f * 64 + (kk & 1) * 32 + lq * 8);
        f32x4 lo = p4[0], hi = p4[1];
        bf16x8 w;
        w[0] = (bf16)lo[0]; w[1] = (bf16)lo[1]; w[2] = (bf16)lo[2]; w[3] = (bf16)lo[3];
        w[4] = (bf16)hi[0]; w[5] = (bf16)hi[1]; w[6] = (bf16)hi[2]; w[7] = (bf16)hi[3];
        wfrag[kk] = w;
    }

    // ---- Fixed A-row base pointers for the MFMA phase ----
    const unsigned char* arow[3];
    #pragma unroll
    for (int mt = 0; mt < 3; ++mt) {
        int m  = mt * 16 + l16;
        int wv = m / 12;
        int r  = m - wv * 12;
        arow[mt] = &lds[wv * WREG + r * 400] + lq * 16;
    }

    // ---- Group loop (fully unrolled: all reg indices static) ----
    #pragma unroll
    for (int g = 0; g < NG; ++g) {
        // Prefetch next group's J/X (consumed a full group-body later)
        float jn[4][6], xn[4][3];
        if (g + 1 < NG)
            load_group(J, X, (gbase + g + 1) * PTS, wave, lane, jn, xn);

        const long bn0 = (gbase + g) * PTS;

        // ---- Terms; write T rows ----
        #pragma unroll
        for (int q = 0; q < 4; ++q) {
            float a1x = jc[q][0], a2x = jc[q][1];
            float a1y = jc[q][2], a2y = jc[q][3];
            float a1z = jc[q][4], a2z = jc[q][5];
            float xx = xc[q][0], xy = xc[q][1], xz = xc[q][2];

            float n1sq = a1x*a1x + a1y*a1y + a1z*a1z;
            float inv1 = __builtin_amdgcn_rsqf(fmaxf(n1sq, 1e-24f));  // == 1/max(sqrt,1e-12)
            float b1x = a1x*inv1, b1y = a1y*inv1, b1z = a1z*inv1;
            float dot = b1x*a2x + b1y*a2y + b1z*a2z;
            float ux = a2x - dot*b1x, uy = a2y - dot*b1y, uz = a2z - dot*b1z;
            float n2sq = ux*ux + uy*uy + uz*uz;
            float inv2 = __builtin_amdgcn_rsqf(fmaxf(n2sq, 1e-24f));
            float b2x = ux*inv2, b2y = uy*inv2, b2z = uz*inv2;
            float b3x = b1y*b2z - b1z*b2y;
            float b3y = b1z*b2x - b1x*b2z;
            float b3z = b1x*b2y - b1y*b2x;

            float rt0 = b1x*xx + b1y*xy + b1z*xz;
            float rt1 = b2x*xx + b2y*xy + b2z*xz;
            float rt2 = b3x*xx + b3y*xy + b3z*xz;

            float at0 = b1x*rt0 + b2x*rt1;
            float at1 = b1y*rt0 + b2y*rt1;
            float at2 = b1z*rt0 + b2z*rt1;
            float bt0 = b2x*rt0 - b1x*rt1;
            float bt1 = b2y*rt0 - b1y*rt1;
            float bt2 = b2z*rt0 - b1z*rt1;
            float ct0 = b3x*rt2, ct1 = b3y*rt2, ct2 = b3z*rt2;

            bf16* r0 = (bf16*)(wbase + (q*3 + 0) * 400);
            bf16* r1 = (bf16*)(wbase + (q*3 + 1) * 400);
            bf16* r2 = (bf16*)(wbase + (q*3 + 2) * 400);
            r0[lane] = (bf16)at0; r0[64+lane] = (bf16)bt0; r0[128+lane] = (bf16)ct0;
            r1[lane] = (bf16)at1; r1[64+lane] = (bf16)bt1; r1[128+lane] = (bf16)ct1;
            r2[lane] = (bf16)at2; r2[64+lane] = (bf16)bt2; r2[128+lane] = (bf16)ct2;
        }

        // barrier 1: publish T. lgkm-only wait — prefetch loads stay in flight.
        __asm__ volatile("s_waitcnt lgkmcnt(0)" ::: "memory");
        __builtin_amdgcn_s_barrier();

        // ---- MFMA: D[m,f] = sum_k T[m,k] * W[f,k] ----
        f32x4 acc[3];
        #pragma unroll
        for (int mt = 0; mt < 3; ++mt) acc[mt] = (f32x4){0.f, 0.f, 0.f, 0.f};
        #pragma unroll
        for (int kk = 0; kk < 6; ++kk) {
            #pragma unroll
            for (int mt = 0; mt < 3; ++mt) {
                bf16x8 af = *(const bf16x8*)(arow[mt] + kk * 64);
                acc[mt] = __builtin_amdgcn_mfma_f32_16x16x32_bf16(af, wfrag[kk], acc[mt], 0, 0, 0);
            }
        }

        // barrier 2: all T reads consumed; regions reusable.
        __asm__ volatile("s_waitcnt lgkmcnt(0)" ::: "memory");
        __builtin_amdgcn_s_barrier();

        // ---- Wave-private Y scatter: f-cols [16w,16w+16) => 48 floats per point ----
        float* yw = (float*)wbase;
        #pragma unroll
        for (int mt = 0; mt < 3; ++mt) {
            #pragma unroll
            for (int r = 0; r < 4; ++r) {
                int m  = mt * 16 + lq * 4 + r;
                int wv = m / 12;
                int rr = m - wv * 12;
                int q  = rr / 3;
                int i  = rr - q * 3;
                int p  = wv * 4 + q;
                yw[p * 48 + l16 * 3 + i] = acc[mt][r];
            }
        }

        // ---- Wave-private coalesced writeout: 16 chunks of 192 B ----
        const f32x4* ysrc = (const f32x4*)yw;
        #pragma unroll
        for (int v = 0; v < 3; ++v) {
            int vi = v * 64 + lane;           // 0..191
            int p  = vi / 12;
            int vo = vi - p * 12;
            f32x4* dst = (f32x4*)(Y + (bn0 + p) * 192 + wave * 48) + vo;
            *dst = ysrc[vi];
        }

        // ---- Rotate prefetched regs (SSA-renamed under full unroll) ----
        if (g + 1 < NG) {
            #pragma unroll
            for (int q = 0; q < 4; ++q) {
                #pragma unroll
                for (int k = 0; k < 6; ++k) jc[q][k] = jn[q][k];
                #pragma unroll
                for (int k = 0; k < 3; ++k) xc[q][k] = xn[q][k];
            }
        }
    }
}

extern "C" void kernel_launch(void* const* d_in, const int* in_sizes, int n_in,
                              void* d_out, int out_size, void* d_ws, size_t ws_size,
                              hipStream_t stream) {
    const float* X  = (const float*)d_in[0];
    const float* J  = (const float*)d_in[1];
    const float* A  = (const float*)d_in[2];
    const float* Bm = (const float*)d_in[3];
    const float* C  = (const float*)d_in[4];
    float* Y = (float*)d_out;

    const int points = in_sizes[0] / (64 * 3);   // B*N = 65536
    const int blocks = points / (PTS * NG);      // 1024
    affine_linear_fused<<<blocks, 256, 0, stream>>>(X, J, A, Bm, C, Y);
}